// Round 8
// baseline (113.163 us; speedup 1.0000x reference)
//
#include <hip/hip_runtime.h>
#include <hip/hip_bf16.h>

#define SEQ 4096
#define DM  512

typedef short bf16x8 __attribute__((ext_vector_type(8)));
typedef short s16x4  __attribute__((ext_vector_type(4)));
typedef float f32x4  __attribute__((ext_vector_type(4)));

#define L2E 1.4426950408889634f
#define EXP2(x) __builtin_amdgcn_exp2f(x)
#define MFMA(a, b, c) __builtin_amdgcn_mfma_f32_16x16x32_bf16(a, b, c, 0, 0, 0)

static __device__ __forceinline__ unsigned short f2bf(float f) {
    unsigned int u = __builtin_bit_cast(unsigned int, f);
    unsigned int r = u + 0x7FFFu + ((u >> 16) & 1u);
    return (unsigned short)(r >> 16);
}

static __device__ __forceinline__ bf16x8 cvt8(const float* __restrict__ p, float s) {
    f32x4 a = *(const f32x4*)p;
    f32x4 b = *(const f32x4*)(p + 4);
    bf16x8 r;
    r[0] = (short)f2bf(a[0] * s); r[1] = (short)f2bf(a[1] * s);
    r[2] = (short)f2bf(a[2] * s); r[3] = (short)f2bf(a[3] * s);
    r[4] = (short)f2bf(b[0] * s); r[5] = (short)f2bf(b[1] * s);
    r[6] = (short)f2bf(b[2] * s); r[7] = (short)f2bf(b[3] * s);
    return r;
}

// ---------------------------------------------------------------------------
// Kernel 1: QKV projection straight from f32 inputs (inline cvt), split-K
//   across 4 waves + LDS f32 reduce. grid (SEQ/16, 3), block 256.
//   blockIdx.y: 0=Q (Wq,bq pre-scaled by 1/8 inline), 1=K, 2=V(transposed).
//   Q,K: [SEQ][64] bf16 row-major.  V: VbT[d][n] = V^T, [64][SEQ] bf16.
// ---------------------------------------------------------------------------
__global__ __launch_bounds__(256) void proj_kernel(
    const float* __restrict__ E,
    const float* __restrict__ Wq, const float* __restrict__ bq,
    const float* __restrict__ Wk, const float* __restrict__ bk,
    const float* __restrict__ Wv, const float* __restrict__ bv,
    unsigned short* __restrict__ Qb, unsigned short* __restrict__ Kb,
    unsigned short* __restrict__ VbT)
{
    const int which = blockIdx.y;
    const int bx  = blockIdx.x;
    const int tid = (int)threadIdx.x;
    const int w   = tid >> 6;             // wave 0..3: K-chunk w*128
    const int l   = tid & 63;
    const int lo  = l & 15;
    const int hi  = l >> 4;

    __shared__ float Acc[5120];           // Q/K: [4][16][68]; V: [4][64][20]

    const float* W    = (which == 0) ? Wq : ((which == 1) ? Wk : Wv);
    const float* bias = (which == 0) ? bq : ((which == 1) ? bk : bv);
    const float wscale = (which == 0) ? 0.125f : 1.0f;

    f32x4 acc[4] = {};

    if (which < 2) {
        unsigned short* out = (which == 0) ? Qb : Kb;
        const int r0 = bx * 16;
#pragma unroll
        for (int kk = 0; kk < 4; ++kk) {
            const int k0 = w * 128 + kk * 32;
            bf16x8 a = cvt8(&E[(size_t)(r0 + lo) * DM + k0 + hi * 8], 1.0f);
#pragma unroll
            for (int ct = 0; ct < 4; ++ct) {
                bf16x8 bb = cvt8(&W[(size_t)(lo + 16 * ct) * DM + k0 + hi * 8], wscale);
                acc[ct] = MFMA(a, bb, acc[ct]);
            }
        }
#pragma unroll
        for (int ct = 0; ct < 4; ++ct)
#pragma unroll
            for (int r = 0; r < 4; ++r)
                Acc[(w * 16 + hi * 4 + r) * 68 + lo + 16 * ct] = acc[ct][r];
        __syncthreads();
        {
            const int row = tid >> 4;
            const int c0  = (tid & 15) * 4;
            f32x4 sum = {};
#pragma unroll
            for (int ww = 0; ww < 4; ++ww)
                sum += *(const f32x4*)&Acc[(ww * 16 + row) * 68 + c0];
            s16x4 o4;
#pragma unroll
            for (int j = 0; j < 4; ++j)
                o4[j] = (short)f2bf(sum[j] + bias[c0 + j] * wscale);
            *(s16x4*)&out[(size_t)(r0 + row) * 64 + c0] = o4;
        }
    } else {
        const int n0 = bx * 16;
#pragma unroll
        for (int kk = 0; kk < 4; ++kk) {
            const int k0 = w * 128 + kk * 32;
            bf16x8 bb = cvt8(&E[(size_t)(n0 + lo) * DM + k0 + hi * 8], 1.0f);
#pragma unroll
            for (int ct = 0; ct < 4; ++ct) {
                bf16x8 a = cvt8(&W[(size_t)(lo + 16 * ct) * DM + k0 + hi * 8], 1.0f);
                acc[ct] = MFMA(a, bb, acc[ct]);
            }
        }
#pragma unroll
        for (int ct = 0; ct < 4; ++ct)
#pragma unroll
            for (int r = 0; r < 4; ++r)
                Acc[(w * 64 + 16 * ct + hi * 4 + r) * 20 + lo] = acc[ct][r];
        __syncthreads();
        {
            const int d  = tid >> 2;
            const int n4 = (tid & 3) * 4;
            f32x4 sum = {};
#pragma unroll
            for (int ww = 0; ww < 4; ++ww)
                sum += *(const f32x4*)&Acc[(ww * 64 + d) * 20 + n4];
            const float bd = bias[d];
            s16x4 o4;
#pragma unroll
            for (int j = 0; j < 4; ++j)
                o4[j] = (short)f2bf(sum[j] + bd);
            *(s16x4*)&VbT[(size_t)d * SEQ + n0 + n4] = o4;
        }
    }
}

// ---------------------------------------------------------------------------
// Kernel 2: causal flash attention, single pass, 8 waves per block,
//   128 keys per wave-iteration (two 64-key sub-blocks; second guarded by
//   wave-uniform hasB). One shfl-reduce + one alpha + one O-rescale per 128
//   keys. No compiler memory fences in the loop: Pl write->read ordering is
//   preserved by LDS alias analysis (same array), letting the compiler
//   software-pipeline loads across iterations.
// ---------------------------------------------------------------------------
__global__ __launch_bounds__(512) void attn_kernel(
    const unsigned short* __restrict__ Qb,
    const unsigned short* __restrict__ Kb,
    const unsigned short* __restrict__ VbT,
    float* __restrict__ out)
{
    const int q0  = blockIdx.x * 16;
    const int tid = (int)threadIdx.x;
    const int w   = tid >> 6;
    const int l   = tid & 63;
    const int lo  = l & 15;
    const int hi  = l >> 4;

    __shared__ unsigned short Pl[8][16][136];  // 128 P-cols + 8 pad
    __shared__ float Osh[8][16][64];
    __shared__ float msh[8][16];
    __shared__ float lsh[8][16];

    bf16x8 qf0 = *(const bf16x8*)&Qb[(size_t)(q0 + lo) * 64 + hi * 8];
    bf16x8 qf1 = *(const bf16x8*)&Qb[(size_t)(q0 + lo) * 64 + 32 + hi * 8];

    float m[4], lsum[4];
    f32x4 o[4] = {};
#pragma unroll
    for (int r = 0; r < 4; ++r) { m[r] = -1e30f; lsum[r] = 0.f; }

    const int kend = q0 + 16;
    for (int kb = w * 128; kb < kend; kb += 1024) {
        const bool hasB = (kb + 64 < kend);
        // ---- QK^T: sub-block A (keys kb..kb+63), B (kb+64..kb+127) ----
        f32x4 s[8] = {};
#pragma unroll
        for (int ct = 0; ct < 4; ++ct) {
            const unsigned short* kp = &Kb[(size_t)(kb + lo + 16 * ct) * 64];
            bf16x8 kf0 = *(const bf16x8*)&kp[hi * 8];
            bf16x8 kf1 = *(const bf16x8*)&kp[32 + hi * 8];
            s[ct] = MFMA(qf0, kf0, s[ct]);
            s[ct] = MFMA(qf1, kf1, s[ct]);
        }
        if (hasB) {
#pragma unroll
            for (int ct = 0; ct < 4; ++ct) {
                const unsigned short* kp = &Kb[(size_t)(kb + 64 + lo + 16 * ct) * 64];
                bf16x8 kf0 = *(const bf16x8*)&kp[hi * 8];
                bf16x8 kf1 = *(const bf16x8*)&kp[32 + hi * 8];
                s[4 + ct] = MFMA(qf0, kf0, s[4 + ct]);
                s[4 + ct] = MFMA(qf1, kf1, s[4 + ct]);
            }
        }
        // ---- causal mask (at most one partial sub-block per q-tile) ----
        if (kb + 63 > q0) {
#pragma unroll
            for (int ct = 0; ct < 4; ++ct) {
                int key = kb + lo + 16 * ct;
#pragma unroll
                for (int r = 0; r < 4; ++r)
                    if (key > q0 + hi * 4 + r) s[ct][r] = -3.0e38f;
            }
        }
        if (hasB && (kb + 127 > q0)) {
#pragma unroll
            for (int ct = 0; ct < 4; ++ct) {
                int key = kb + 64 + lo + 16 * ct;
#pragma unroll
                for (int r = 0; r < 4; ++r)
                    if (key > q0 + hi * 4 + r) s[4 + ct][r] = -3.0e38f;
            }
        }
        // ---- row max over present sub-blocks ----
        float mt[4] = { -1e30f, -1e30f, -1e30f, -1e30f };
#pragma unroll
        for (int ct = 0; ct < 4; ++ct)
#pragma unroll
            for (int r = 0; r < 4; ++r) mt[r] = fmaxf(mt[r], s[ct][r]);
        if (hasB) {
#pragma unroll
            for (int ct = 0; ct < 4; ++ct)
#pragma unroll
                for (int r = 0; r < 4; ++r) mt[r] = fmaxf(mt[r], s[4 + ct][r]);
        }
#pragma unroll
        for (int mask = 1; mask < 16; mask <<= 1)
#pragma unroll
            for (int r = 0; r < 4; ++r) mt[r] = fmaxf(mt[r], __shfl_xor(mt[r], mask));
        // ---- online softmax update (once per 128 keys) ----
        float alpha[4], mn[4];
#pragma unroll
        for (int r = 0; r < 4; ++r) {
            mn[r] = fmaxf(m[r], mt[r]);
            alpha[r] = EXP2((m[r] - mn[r]) * L2E);
            m[r] = mn[r];
        }
        float ps[4] = { 0.f, 0.f, 0.f, 0.f };
#pragma unroll
        for (int ct = 0; ct < 4; ++ct) {
#pragma unroll
            for (int r = 0; r < 4; ++r) {
                float p = EXP2((s[ct][r] - mn[r]) * L2E);
                ps[r] += p;
                Pl[w][hi * 4 + r][lo + 16 * ct] = f2bf(p);
            }
        }
        if (hasB) {
#pragma unroll
            for (int ct = 0; ct < 4; ++ct) {
#pragma unroll
                for (int r = 0; r < 4; ++r) {
                    float p = EXP2((s[4 + ct][r] - mn[r]) * L2E);
                    ps[r] += p;
                    Pl[w][hi * 4 + r][64 + lo + 16 * ct] = f2bf(p);
                }
            }
        }
#pragma unroll
        for (int mask = 1; mask < 16; mask <<= 1)
#pragma unroll
            for (int r = 0; r < 4; ++r) ps[r] += __shfl_xor(ps[r], mask);
#pragma unroll
        for (int r = 0; r < 4; ++r) lsum[r] = lsum[r] * alpha[r] + ps[r];
#pragma unroll
        for (int dt = 0; dt < 4; ++dt)
#pragma unroll
            for (int r = 0; r < 4; ++r) o[dt][r] *= alpha[r];
        // ---- PV over 128 keys ----
        bf16x8 pa0 = *(const bf16x8*)&Pl[w][lo][hi * 8];
        bf16x8 pa1 = *(const bf16x8*)&Pl[w][lo][32 + hi * 8];
#pragma unroll
        for (int dt = 0; dt < 4; ++dt) {
            const unsigned short* vp = &VbT[(size_t)(lo + 16 * dt) * SEQ + kb];
            bf16x8 v0 = *(const bf16x8*)&vp[hi * 8];
            bf16x8 v1 = *(const bf16x8*)&vp[32 + hi * 8];
            o[dt] = MFMA(pa0, v0, o[dt]);
            o[dt] = MFMA(pa1, v1, o[dt]);
        }
        if (hasB) {
            bf16x8 pa2 = *(const bf16x8*)&Pl[w][lo][64 + hi * 8];
            bf16x8 pa3 = *(const bf16x8*)&Pl[w][lo][96 + hi * 8];
#pragma unroll
            for (int dt = 0; dt < 4; ++dt) {
                const unsigned short* vp = &VbT[(size_t)(lo + 16 * dt) * SEQ + kb + 64];
                bf16x8 v2 = *(const bf16x8*)&vp[hi * 8];
                bf16x8 v3 = *(const bf16x8*)&vp[32 + hi * 8];
                o[dt] = MFMA(pa2, v2, o[dt]);
                o[dt] = MFMA(pa3, v3, o[dt]);
            }
        }
    }

    // ---- stage wave partials in LDS ----
#pragma unroll
    for (int dt = 0; dt < 4; ++dt)
#pragma unroll
        for (int r = 0; r < 4; ++r)
            Osh[w][hi * 4 + r][lo + 16 * dt] = o[dt][r];
    if (lo == 0) {
#pragma unroll
        for (int r = 0; r < 4; ++r) {
            msh[w][hi * 4 + r] = m[r];
            lsh[w][hi * 4 + r] = lsum[r];
        }
    }
    __syncthreads();

    // ---- combine the 8 wave partials (LSE), write normalized output ----
    {
        const int q  = tid >> 5;
        const int d0 = (tid & 31) * 2;
        float M = msh[0][q];
#pragma unroll
        for (int ww = 1; ww < 8; ++ww) M = fmaxf(M, msh[ww][q]);
        float L = 0.f, a0 = 0.f, a1 = 0.f;
#pragma unroll
        for (int ww = 0; ww < 8; ++ww) {
            float e = EXP2((msh[ww][q] - M) * L2E);
            L  += e * lsh[ww][q];
            a0 += e * Osh[ww][q][d0];
            a1 += e * Osh[ww][q][d0 + 1];
        }
        float inv = 1.0f / L;
        out[(size_t)(q0 + q) * 64 + d0]     = a0 * inv;
        out[(size_t)(q0 + q) * 64 + d0 + 1] = a1 * inv;
    }
}

// ---------------------------------------------------------------------------
extern "C" void kernel_launch(void* const* d_in, const int* in_sizes, int n_in,
                              void* d_out, int out_size, void* d_ws, size_t ws_size,
                              hipStream_t stream) {
    const float* E  = (const float*)d_in[0];
    const float* Wq = (const float*)d_in[1];
    const float* bq = (const float*)d_in[2];
    const float* Wk = (const float*)d_in[3];
    const float* bk = (const float*)d_in[4];
    const float* Wv = (const float*)d_in[5];
    const float* bv = (const float*)d_in[6];
    float* out = (float*)d_out;

    char* ws = (char*)d_ws;
    unsigned short* Qb  = (unsigned short*)(ws);                    // 512 KB
    unsigned short* Kb  = (unsigned short*)(ws + (512u << 10));     // 512 KB
    unsigned short* VbT = (unsigned short*)(ws + (1024u << 10));    // 512 KB

    hipLaunchKernelGGL(proj_kernel, dim3(SEQ / 16, 3), dim3(256), 0, stream,
                       E, Wq, bq, Wk, bk, Wv, bv, Qb, Kb, VbT);
    hipLaunchKernelGGL(attn_kernel, dim3(SEQ / 16), dim3(512), 0, stream,
                       Qb, Kb, VbT, out);
}